// Round 9
// baseline (241.136 us; speedup 1.0000x reference)
//
#include <hip/hip_runtime.h>
#include <hip/hip_bf16.h>

typedef __hip_bfloat16 bf16;
typedef __attribute__((ext_vector_type(8))) short short8;
typedef __attribute__((ext_vector_type(4))) float f32x4;

#define NN 128
#define DD_ 64
#define HH_ 8
#define DH_ 64
#define DI_ 512
#define SS_ 5
#define MLPD 1024
#define SDI 2560

// pr region bases (floats)
#define PR_B0 0
#define PR_B1 262144
#define PR_B2 1048576
#define PR_B3 2359296
#define PR_B4 3145728
#define PR_TOT 4456448

__device__ __forceinline__ float wave_sum64(float v) {
#pragma unroll
    for (int off = 32; off > 0; off >>= 1) v += __shfl_xor(v, off, 64);
    return v;
}

__device__ __forceinline__ unsigned short f2bf_u(float f) {
    unsigned u = __float_as_uint(f);
    u += 0x7FFF + ((u >> 16) & 1);
    return (unsigned short)(u >> 16);
}
__device__ __forceinline__ float bfu2f(unsigned short s) {
    return __uint_as_float(((unsigned)s) << 16);
}
__device__ __forceinline__ unsigned pk2(unsigned short a, unsigned short b) {
    return (unsigned)a | ((unsigned)b << 16);
}

// K1: fused LN + q/k + mlp1, column-chunked. grid(128 i, 4 ch), block(256).
__global__ __launch_bounds__(256) void k_front(
    const float* __restrict__ h, const float* __restrict__ ghi, const float* __restrict__ ghj,
    const float* __restrict__ Wq, const float* __restrict__ Wk,
    const float* __restrict__ Wv1, const float* __restrict__ bv1,
    const float* __restrict__ Wp1, const float* __restrict__ bp1,
    float* __restrict__ q, float* __restrict__ k,
    float* __restrict__ a1, float* __restrict__ p1) {
    int i = blockIdx.x, ch = blockIdx.y, t = threadIdx.x;
    int d = t & 63;
    __shared__ float hib[DD_], hjb[DD_];
    float x = h[i * DD_ + d];
    float s = wave_sum64(x);
    float s2 = wave_sum64(x * x);
    float m = s * (1.0f / DD_);
    float v = s2 * (1.0f / DD_) - m * m;
    float r = rsqrtf(v + 1e-5f);
    float xc = (x - m) * r;
    if (t < 64) { hib[d] = xc * ghi[d]; hjb[d] = xc * ghj[d]; }
    __syncthreads();
    {
        int c = ch * 128 + (t & 127);
        const float* W = (t < 128) ? Wq : Wk;
        const float* hb = (t < 128) ? hib : hjb;
        float a = 0.f;
#pragma unroll 8
        for (int dd = 0; dd < DD_; dd++) a += hb[dd] * W[dd * DI_ + c];
        float* dstqk = (t < 128) ? q : k;
        dstqk[i * DI_ + c] = a;
    }
    {
        int c = ch * 256 + t;
        float av = 0.f, ap = 0.f;
#pragma unroll 4
        for (int dd = 0; dd < DD_; dd++) {
            float hv = hjb[dd];
            av += hv * Wv1[dd * MLPD + c];
            ap += hv * Wp1[dd * MLPD + c];
        }
        float xv = av + bv1[c], xp = ap + bp1[c];
        a1[i * MLPD + c] = xv / (1.0f + expf(-xv));
        p1[i * MLPD + c] = xp / (1.0f + expf(-xp));
    }
}

// K4: split-K MFMA GEMM (hi/lo bf16 compensation): part[ks][j][cc].
// grid(80 ct, 4 ks), block(256).
#define KS2 4
__global__ __launch_bounds__(256) void k_mlp2(const float* __restrict__ a1,
                                              const float* __restrict__ p1,
                                              const float* __restrict__ Wv2,
                                              const float* __restrict__ Wp2,
                                              float* __restrict__ part) {
    int ct = blockIdx.x, ks = blockIdx.y, t = threadIdx.x;
    int c0 = ct * 64;
    bool isp = c0 >= 2560;
    int c0l = c0 - (isp ? 2560 : 0);
    const float* __restrict__ src = isp ? p1 : a1;
    const float* __restrict__ W = isp ? Wp2 : Wv2;
    int kbase = ks * 256;
    __shared__ unsigned short Ahi[128][40], Alo[128][40];
    __shared__ unsigned short Bhi[64][40], Blo[64][40];
    int lane = t & 63, wv = t >> 6;
    int l15 = lane & 15, quad = lane >> 4;
    f32x4 acc[2][4];
#pragma unroll
    for (int mt = 0; mt < 2; mt++)
#pragma unroll
        for (int nt = 0; nt < 4; nt++) acc[mt][nt] = (f32x4){0.f, 0.f, 0.f, 0.f};
    int aj = t >> 1, ak = (t & 1) * 16;
    int bc = t & 63, bk = (t >> 6) * 8;
    for (int kc = 0; kc < 8; kc++) {
        int k0 = kbase + kc * 32;
        __syncthreads();
        {
            unsigned short h16[16], l16[16];
            const float* ap = &src[(size_t)aj * MLPD + k0 + ak];
#pragma unroll
            for (int e = 0; e < 16; e += 4) {
                float4 v = *(const float4*)(ap + e);
                float vv[4] = {v.x, v.y, v.z, v.w};
#pragma unroll
                for (int z = 0; z < 4; z++) {
                    unsigned short hb = f2bf_u(vv[z]);
                    h16[e + z] = hb;
                    l16[e + z] = f2bf_u(vv[z] - bfu2f(hb));
                }
            }
            *(uint4*)&Ahi[aj][ak] = make_uint4(pk2(h16[0], h16[1]), pk2(h16[2], h16[3]),
                                               pk2(h16[4], h16[5]), pk2(h16[6], h16[7]));
            *(uint4*)&Ahi[aj][ak + 8] = make_uint4(pk2(h16[8], h16[9]), pk2(h16[10], h16[11]),
                                                   pk2(h16[12], h16[13]), pk2(h16[14], h16[15]));
            *(uint4*)&Alo[aj][ak] = make_uint4(pk2(l16[0], l16[1]), pk2(l16[2], l16[3]),
                                               pk2(l16[4], l16[5]), pk2(l16[6], l16[7]));
            *(uint4*)&Alo[aj][ak + 8] = make_uint4(pk2(l16[8], l16[9]), pk2(l16[10], l16[11]),
                                                   pk2(l16[12], l16[13]), pk2(l16[14], l16[15]));
        }
        {
            unsigned short h8[8], l8[8];
#pragma unroll
            for (int e = 0; e < 8; e++) {
                float v = W[(size_t)(k0 + bk + e) * SDI + c0l + bc];
                unsigned short hb = f2bf_u(v);
                h8[e] = hb;
                l8[e] = f2bf_u(v - bfu2f(hb));
            }
            *(uint4*)&Bhi[bc][bk] = make_uint4(pk2(h8[0], h8[1]), pk2(h8[2], h8[3]),
                                               pk2(h8[4], h8[5]), pk2(h8[6], h8[7]));
            *(uint4*)&Blo[bc][bk] = make_uint4(pk2(l8[0], l8[1]), pk2(l8[2], l8[3]),
                                               pk2(l8[4], l8[5]), pk2(l8[6], l8[7]));
        }
        __syncthreads();
        int ko = quad * 8;
        short8 a_h0 = *(const short8*)&Ahi[(wv * 2 + 0) * 16 + l15][ko];
        short8 a_l0 = *(const short8*)&Alo[(wv * 2 + 0) * 16 + l15][ko];
        short8 a_h1 = *(const short8*)&Ahi[(wv * 2 + 1) * 16 + l15][ko];
        short8 a_l1 = *(const short8*)&Alo[(wv * 2 + 1) * 16 + l15][ko];
#pragma unroll
        for (int nt = 0; nt < 4; nt++) {
            short8 b_h = *(const short8*)&Bhi[nt * 16 + l15][ko];
            short8 b_l = *(const short8*)&Blo[nt * 16 + l15][ko];
            acc[0][nt] = __builtin_amdgcn_mfma_f32_16x16x32_bf16(a_h0, b_h, acc[0][nt], 0, 0, 0);
            acc[0][nt] = __builtin_amdgcn_mfma_f32_16x16x32_bf16(a_h0, b_l, acc[0][nt], 0, 0, 0);
            acc[0][nt] = __builtin_amdgcn_mfma_f32_16x16x32_bf16(a_l0, b_h, acc[0][nt], 0, 0, 0);
            acc[1][nt] = __builtin_amdgcn_mfma_f32_16x16x32_bf16(a_h1, b_h, acc[1][nt], 0, 0, 0);
            acc[1][nt] = __builtin_amdgcn_mfma_f32_16x16x32_bf16(a_h1, b_l, acc[1][nt], 0, 0, 0);
            acc[1][nt] = __builtin_amdgcn_mfma_f32_16x16x32_bf16(a_l1, b_h, acc[1][nt], 0, 0, 0);
        }
    }
#pragma unroll
    for (int mt = 0; mt < 2; mt++)
#pragma unroll
        for (int nt = 0; nt < 4; nt++)
#pragma unroll
            for (int r = 0; r < 4; r++) {
                int j = (wv * 2 + mt) * 16 + quad * 4 + r;
                int cc = c0 + nt * 16 + l15;
                part[(size_t)ks * 655360 + (size_t)j * 5120 + cc] = acc[mt][nt][r];
            }
}

// K_postM: part-reduce -> vals slice (LDS) -> VC; part-reduce -> pav slice (LDS P) -> M.
// grid(128 j, 5 s), block(256).
__global__ __launch_bounds__(256) void k_postM(const float* __restrict__ part,
                                               const float* __restrict__ bv2,
                                               const float* __restrict__ bp2,
                                               const float* __restrict__ Wc,
                                               const float* __restrict__ Wev,
                                               float* __restrict__ VC,
                                               float* __restrict__ M) {
    int j = blockIdx.x, s = blockIdx.y, t = threadIdx.x;
    int lane = t & 63, w = t >> 6;
    __shared__ float vlds[DI_];
    __shared__ float P[DI_];
    __shared__ unsigned short Ahi[64][72], Alo[64][72];
    __shared__ unsigned short Bhi[64][72], Blo[64][72];
#pragma unroll
    for (int r = 0; r < 2; r++) {
        int o = t + r * 256;
        int ev = s * 512 + o;
        int ep = 2560 + s * 512 + o;
        float sv = 0.f, sp = 0.f;
#pragma unroll
        for (int p = 0; p < KS2; p++) {
            sv += part[(size_t)p * 655360 + (size_t)j * 5120 + ev];
            sp += part[(size_t)p * 655360 + (size_t)j * 5120 + ep];
        }
        vlds[o] = sv + bv2[ev];
        P[o] = sp + bp2[s * 512 + o];
    }
    __syncthreads();
    // VC: 512 outputs, 2 per thread
#pragma unroll
    for (int r = 0; r < 2; r++) {
        int o = t + r * 256;
        int dd = o & 63;
        int hb = o - dd;  // h*64
        float acc2 = 0.f;
#pragma unroll 8
        for (int d2 = 0; d2 < DH_; d2++) acc2 += vlds[hb + d2] * Wc[(size_t)(hb + d2) * DD_ + dd];
        VC[(size_t)(j * SS_ + s) * DI_ + o] = acc2;
    }
    // M via MFMA hi/lo compensation, P from LDS
    f32x4 acc[4];
#pragma unroll
    for (int n = 0; n < 4; n++) acc[n] = (f32x4){0.f, 0.f, 0.f, 0.f};
    for (int u0 = 0; u0 < DI_; u0 += 64) {
        __syncthreads();
        {
            int c = t >> 2, ug = (t & 3) * 16;
            const float* wevp = &Wev[(size_t)c * SDI + s * DI_ + u0 + ug];
            unsigned short ah[16], al[16];
#pragma unroll
            for (int e = 0; e < 16; e += 4) {
                float4 wv2 = *(const float4*)(wevp + e);
                float4 pv = *(const float4*)&P[u0 + ug + e];
                float av[4] = {wv2.x * pv.x, wv2.y * pv.y, wv2.z * pv.z, wv2.w * pv.w};
#pragma unroll
                for (int z = 0; z < 4; z++) {
                    unsigned short hh2 = f2bf_u(av[z]);
                    ah[e + z] = hh2;
                    al[e + z] = f2bf_u(av[z] - bfu2f(hh2));
                }
            }
            *(uint4*)&Ahi[c][ug] = make_uint4(pk2(ah[0], ah[1]), pk2(ah[2], ah[3]),
                                              pk2(ah[4], ah[5]), pk2(ah[6], ah[7]));
            *(uint4*)&Ahi[c][ug + 8] = make_uint4(pk2(ah[8], ah[9]), pk2(ah[10], ah[11]),
                                                  pk2(ah[12], ah[13]), pk2(ah[14], ah[15]));
            *(uint4*)&Alo[c][ug] = make_uint4(pk2(al[0], al[1]), pk2(al[2], al[3]),
                                              pk2(al[4], al[5]), pk2(al[6], al[7]));
            *(uint4*)&Alo[c][ug + 8] = make_uint4(pk2(al[8], al[9]), pk2(al[10], al[11]),
                                                  pk2(al[12], al[13]), pk2(al[14], al[15]));
        }
        {
            int dd = t & 63, ub = (t >> 6) * 16;
            unsigned short bh[16], bl[16];
#pragma unroll
            for (int e = 0; e < 16; e++) {
                float v = Wc[(size_t)(u0 + ub + e) * DD_ + dd];
                unsigned short hh2 = f2bf_u(v);
                bh[e] = hh2;
                bl[e] = f2bf_u(v - bfu2f(hh2));
            }
            *(uint4*)&Bhi[dd][ub] = make_uint4(pk2(bh[0], bh[1]), pk2(bh[2], bh[3]),
                                               pk2(bh[4], bh[5]), pk2(bh[6], bh[7]));
            *(uint4*)&Bhi[dd][ub + 8] = make_uint4(pk2(bh[8], bh[9]), pk2(bh[10], bh[11]),
                                                   pk2(bh[12], bh[13]), pk2(bh[14], bh[15]));
            *(uint4*)&Blo[dd][ub] = make_uint4(pk2(bl[0], bl[1]), pk2(bl[2], bl[3]),
                                               pk2(bl[4], bl[5]), pk2(bl[6], bl[7]));
            *(uint4*)&Blo[dd][ub + 8] = make_uint4(pk2(bl[8], bl[9]), pk2(bl[10], bl[11]),
                                                   pk2(bl[12], bl[13]), pk2(bl[14], bl[15]));
        }
        __syncthreads();
#pragma unroll
        for (int kk = 0; kk < 2; kk++) {
            int ko = kk * 32 + (lane >> 4) * 8;
            short8 a_h = *(const short8*)&Ahi[w * 16 + (lane & 15)][ko];
            short8 a_l = *(const short8*)&Alo[w * 16 + (lane & 15)][ko];
#pragma unroll
            for (int n = 0; n < 4; n++) {
                short8 b_h = *(const short8*)&Bhi[n * 16 + (lane & 15)][ko];
                short8 b_l = *(const short8*)&Blo[n * 16 + (lane & 15)][ko];
                acc[n] = __builtin_amdgcn_mfma_f32_16x16x32_bf16(a_h, b_h, acc[n], 0, 0, 0);
                acc[n] = __builtin_amdgcn_mfma_f32_16x16x32_bf16(a_h, b_l, acc[n], 0, 0, 0);
                acc[n] = __builtin_amdgcn_mfma_f32_16x16x32_bf16(a_l, b_h, acc[n], 0, 0, 0);
            }
        }
    }
    float* Mp = &M[(size_t)(j * SS_ + s) * 4096];
#pragma unroll
    for (int n = 0; n < 4; n++)
#pragma unroll
        for (int r = 0; r < 4; r++) {
            int c = w * 16 + (lane >> 4) * 4 + r;
            int dd = n * 16 + (lane & 15);
            Mp[c * 64 + dd] = acc[n][r];
        }
}

// K_densim: y<2 -> den halves (T-sum + EV + rsd); y==2 -> simnum. grid(128 i, 3), block(640).
__global__ __launch_bounds__(640) void k_densim(const float* __restrict__ tij,
                                                const float* __restrict__ Wev,
                                                const float* __restrict__ q,
                                                const float* __restrict__ k,
                                                float* __restrict__ rsd,
                                                float* __restrict__ sn) {
    int i = blockIdx.x, y = blockIdx.y, t = threadIdx.x;
    __shared__ float red[10][64];
    __shared__ float Tl[64];
    __shared__ float ql[DI_];
    if (y < 2) {
        int half = y;
        int c = t & 63, jw = t >> 6;
        float s = 0.f;
        for (int j = jw; j < NN; j += 10) s += tij[(size_t)(i * NN + j) * DD_ + c];
        red[jw][c] = s;
        if (t < DI_) ql[t] = q[i * DI_ + t];
        __syncthreads();
        if (t < 64) {
            float a = 0.f;
#pragma unroll
            for (int r2 = 0; r2 < 10; r2++) a += red[r2][t];
            Tl[t] = a;
        }
        __syncthreads();
#pragma unroll
        for (int kx = 0; kx < 2; kx++) {
            int u = half * 1280 + kx * 640 + t;
            float ev = 0.f;
#pragma unroll 8
            for (int cc = 0; cc < DD_; cc++) ev += Tl[cc] * Wev[(size_t)cc * SDI + u];
            float den = wave_sum64(ev * ql[u & 511]);
            if ((t & 63) == 0) {
                int g = u >> 6;
                int ss = g >> 3, hh = g & 7;
                rsd[i * 40 + hh * SS_ + ss] = 1.0f / den;
            }
        }
    } else {
        if (t < DI_) ql[t] = q[i * DI_ + t];
        __syncthreads();
        for (int e = t; e < 1024; e += 640) {
            int hh = e >> 7, j = e & 127;
            float a = 0.f;
            const float* kr = &k[(size_t)j * DI_ + hh * DH_];
            const float* qr = &ql[hh * DH_];
#pragma unroll 8
            for (int d = 0; d < DH_; d++) a += qr[d] * kr[d];
            sn[i * 1024 + hh * NN + j] = a;
        }
    }
}

// K_outred: fused out-computation (MFMA) + j-partial-reduction.
// grid(32 jc, 5 s, 2 ic), block(256). Each block: 4 j x 64 i x one s.
__global__ __launch_bounds__(256) void k_outred(
    const float* __restrict__ M, const float* __restrict__ VC,
    const float* __restrict__ sn, const float* __restrict__ rsd,
    const float* __restrict__ tij,
    const float* __restrict__ r1, const float* __restrict__ r2,
    const float* __restrict__ x1, const float* __restrict__ x2,
    float* __restrict__ pr) {
    int jc = blockIdx.x, s = blockIdx.y, ic = blockIdx.z, t = threadIdx.x;
    int lane = t & 63, wv = t >> 6, l15 = lane & 15, quad = lane >> 4;
    __shared__ unsigned short Ahi[64][40], Alo[64][40];
    __shared__ unsigned short Bhi[64][40], Blo[64][40];
    __shared__ float wl[320];
    int Lm = (s == 2 || s == 4) ? 5 : 3;
    float accW[5][4][4];
#pragma unroll
    for (int m = 0; m < 5; m++)
#pragma unroll
        for (int nt = 0; nt < 4; nt++)
#pragma unroll
            for (int r = 0; r < 4; r++) accW[m][nt][r] = 0.f;
    int i0 = ic * 64;
    for (int jj = 0; jj < 4; jj++) {
        int j = jc * 4 + jj;
        f32x4 acc_o[4];
#pragma unroll
        for (int nt = 0; nt < 4; nt++) acc_o[nt] = (f32x4){0.f, 0.f, 0.f, 0.f};
        __syncthreads();  // protect wl/Ahi from previous iteration readers
        // stage weights for this j
        if (s == 1) {
            for (int e = t; e < 192; e += 256) wl[e] = r1[((i0 + e / 3) * NN + j) * 3 + e % 3];
        } else if (s == 2) {
            for (int e = t; e < 320; e += 256) wl[e] = r2[((i0 + e / 5) * NN + j) * 5 + e % 5];
        } else if (s == 3) {
            for (int e = t; e < 192; e += 256) wl[e] = x1[((size_t)j * DD_ + e / 3) * 3 + e % 3];
        } else if (s == 4) {
            for (int e = t; e < 320; e += 256) wl[e] = x2[((size_t)j * DD_ + e / 5) * 5 + e % 5];
        }
        // phase 0 staging: snr (A, k 0..7 + zeros) / VC (B, k 0..7 + zeros)
        {
            int il = t >> 2, hg = (t & 3) * 2;
            int ii = i0 + il;
            float v0 = sn[ii * 1024 + hg * NN + j] * rsd[ii * 40 + hg * SS_ + s];
            float v1 = sn[ii * 1024 + (hg + 1) * NN + j] * rsd[ii * 40 + (hg + 1) * SS_ + s];
            unsigned short h0 = f2bf_u(v0), h1 = f2bf_u(v1);
            unsigned short g0 = f2bf_u(v0 - bfu2f(h0)), g1 = f2bf_u(v1 - bfu2f(h1));
            *(unsigned*)&Ahi[il][hg] = pk2(h0, h1);
            *(unsigned*)&Alo[il][hg] = pk2(g0, g1);
            if (t < 192) {
                int row = t / 3, g = t % 3;
                *(uint4*)&Ahi[row][8 + g * 8] = make_uint4(0, 0, 0, 0);
                *(uint4*)&Alo[row][8 + g * 8] = make_uint4(0, 0, 0, 0);
            }
            if (t < 64) {
                unsigned short h8[8], l8[8];
#pragma unroll
                for (int e = 0; e < 8; e++) {
                    float v = VC[(size_t)(j * SS_ + s) * DI_ + e * 64 + t];
                    unsigned short hb = f2bf_u(v);
                    h8[e] = hb;
                    l8[e] = f2bf_u(v - bfu2f(hb));
                }
                *(uint4*)&Bhi[t][0] = make_uint4(pk2(h8[0], h8[1]), pk2(h8[2], h8[3]),
                                                 pk2(h8[4], h8[5]), pk2(h8[6], h8[7]));
                *(uint4*)&Blo[t][0] = make_uint4(pk2(l8[0], l8[1]), pk2(l8[2], l8[3]),
                                                 pk2(l8[4], l8[5]), pk2(l8[6], l8[7]));
            } else {
                int idx = t - 64;
                int row = idx / 3, g = idx % 3;
                *(uint4*)&Bhi[row][8 + g * 8] = make_uint4(0, 0, 0, 0);
                *(uint4*)&Blo[row][8 + g * 8] = make_uint4(0, 0, 0, 0);
            }
        }
        __syncthreads();
        {
            int ko = quad * 8;
            short8 a_h = *(const short8*)&Ahi[wv * 16 + l15][ko];
            short8 a_l = *(const short8*)&Alo[wv * 16 + l15][ko];
#pragma unroll
            for (int nt = 0; nt < 4; nt++) {
                short8 b_h = *(const short8*)&Bhi[nt * 16 + l15][ko];
                short8 b_l = *(const short8*)&Blo[nt * 16 + l15][ko];
                acc_o[nt] = __builtin_amdgcn_mfma_f32_16x16x32_bf16(a_h, b_h, acc_o[nt], 0, 0, 0);
                acc_o[nt] = __builtin_amdgcn_mfma_f32_16x16x32_bf16(a_h, b_l, acc_o[nt], 0, 0, 0);
                acc_o[nt] = __builtin_amdgcn_mfma_f32_16x16x32_bf16(a_l, b_h, acc_o[nt], 0, 0, 0);
            }
        }
        // phases 1,2: A = tij c-halves, B = M^T
        for (int kc = 0; kc < 2; kc++) {
            __syncthreads();
            {
                int il = t >> 2, cg = (t & 3) * 8;
                const float* tp = &tij[(size_t)((i0 + il) * NN + j) * DD_ + kc * 32 + cg];
                float4 va = *(const float4*)tp;
                float4 vb = *(const float4*)(tp + 4);
                float vv[8] = {va.x, va.y, va.z, va.w, vb.x, vb.y, vb.z, vb.w};
                unsigned short h8[8], l8[8];
#pragma unroll
                for (int z = 0; z < 8; z++) {
                    unsigned short hb = f2bf_u(vv[z]);
                    h8[z] = hb;
                    l8[z] = f2bf_u(vv[z] - bfu2f(hb));
                }
                *(uint4*)&Ahi[il][cg] = make_uint4(pk2(h8[0], h8[1]), pk2(h8[2], h8[3]),
                                                   pk2(h8[4], h8[5]), pk2(h8[6], h8[7]));
                *(uint4*)&Alo[il][cg] = make_uint4(pk2(l8[0], l8[1]), pk2(l8[2], l8[3]),
                                                   pk2(l8[4], l8[5]), pk2(l8[6], l8[7]));
            }
            {
                int dd = t & 63, cg = (t >> 6) * 8;
                unsigned short h8[8], l8[8];
#pragma unroll
                for (int e = 0; e < 8; e++) {
                    float v = M[(size_t)(j * SS_ + s) * 4096 + (size_t)(kc * 32 + cg + e) * 64 + dd];
                    unsigned short hb = f2bf_u(v);
                    h8[e] = hb;
                    l8[e] = f2bf_u(v - bfu2f(hb));
                }
                *(uint4*)&Bhi[dd][cg] = make_uint4(pk2(h8[0], h8[1]), pk2(h8[2], h8[3]),
                                                   pk2(h8[4], h8[5]), pk2(h8[6], h8[7]));
                *(uint4*)&Blo[dd][cg] = make_uint4(pk2(l8[0], l8[1]), pk2(l8[2], l8[3]),
                                                   pk2(l8[4], l8[5]), pk2(l8[6], l8[7]));
            }
            __syncthreads();
            int ko = quad * 8;
            short8 a_h = *(const short8*)&Ahi[wv * 16 + l15][ko];
            short8 a_l = *(const short8*)&Alo[wv * 16 + l15][ko];
#pragma unroll
            for (int nt = 0; nt < 4; nt++) {
                short8 b_h = *(const short8*)&Bhi[nt * 16 + l15][ko];
                short8 b_l = *(const short8*)&Blo[nt * 16 + l15][ko];
                acc_o[nt] = __builtin_amdgcn_mfma_f32_16x16x32_bf16(a_h, b_h, acc_o[nt], 0, 0, 0);
                acc_o[nt] = __builtin_amdgcn_mfma_f32_16x16x32_bf16(a_h, b_l, acc_o[nt], 0, 0, 0);
                acc_o[nt] = __builtin_amdgcn_mfma_f32_16x16x32_bf16(a_l, b_h, acc_o[nt], 0, 0, 0);
            }
        }
        // weighted accumulation over j
        if (s == 0) {
#pragma unroll
            for (int nt = 0; nt < 4; nt++)
#pragma unroll
                for (int r = 0; r < 4; r++) accW[0][nt][r] += acc_o[nt][r];
        } else if (s <= 2) {
            int rb = wv * 16 + quad * 4;
            for (int m = 0; m < Lm; m++)
#pragma unroll
                for (int r = 0; r < 4; r++) {
                    float wgt = wl[(rb + r) * Lm + m];
#pragma unroll
                    for (int nt = 0; nt < 4; nt++) accW[m][nt][r] += wgt * acc_o[nt][r];
                }
        } else {
            for (int m = 0; m < Lm; m++)
#pragma unroll
                for (int nt = 0; nt < 4; nt++) {
                    float wgt = wl[(nt * 16 + l15) * Lm + m];
#pragma unroll
                    for (int r = 0; r < 4; r++) accW[m][nt][r] += wgt * acc_o[nt][r];
                }
        }
    }
    // write partial records
    size_t base = (s == 0) ? PR_B0 : (s == 1) ? PR_B1 : (s == 2) ? PR_B2 : (s == 3) ? PR_B3 : PR_B4;
    if (s == 0) {
#pragma unroll
        for (int nt = 0; nt < 4; nt++)
#pragma unroll
            for (int r = 0; r < 4; r++) {
                int i = i0 + wv * 16 + quad * 4 + r;
                int dd = nt * 16 + l15;
                pr[base + ((size_t)(jc * 128 + i)) * 64 + dd] = accW[0][nt][r];
            }
    } else {
        for (int m = 0; m < Lm; m++)
#pragma unroll
            for (int nt = 0; nt < 4; nt++)
#pragma unroll
                for (int r = 0; r < 4; r++) {
                    int i = i0 + wv * 16 + quad * 4 + r;
                    int dd = nt * 16 + l15;
                    pr[base + (((size_t)(jc * 128 + i)) * 64 + dd) * Lm + m] = accW[m][nt][r];
                }
    }
}

// K_red2: fold 32 jc-partials + combine + store. grid(128), block(320).
__global__ void k_red2(const float* __restrict__ pr, const float* __restrict__ h,
                       float* __restrict__ dst) {
    int i = blockIdx.x, t = threadIdx.x;
    int s = t >> 6, dd = t & 63;
    if (s == 0) {
        float v = 0.f;
        for (int c = 0; c < 32; c++) v += pr[PR_B0 + ((size_t)(c * 128 + i)) * 64 + dd];
        dst[i * DD_ + dd] = h[i * DD_ + dd] + v;
    } else if (s == 3) {
        float v[3] = {0.f, 0.f, 0.f};
        for (int c = 0; c < 32; c++) {
            size_t ro = ((size_t)(c * 128 + i)) * 64 + dd;
#pragma unroll
            for (int m = 0; m < 3; m++)
                v[m] += pr[PR_B1 + ro * 3 + m] + pr[PR_B3 + ro * 3 + m];
        }
#pragma unroll
        for (int m = 0; m < 3; m++)
            dst[8192 + (i * DD_ + dd) * 3 + m] = v[m];
    } else if (s == 4) {
        float v[5] = {0.f, 0.f, 0.f, 0.f, 0.f};
        for (int c = 0; c < 32; c++) {
            size_t ro = ((size_t)(c * 128 + i)) * 64 + dd;
#pragma unroll
            for (int m = 0; m < 5; m++)
                v[m] += pr[PR_B2 + ro * 5 + m] + pr[PR_B4 + ro * 5 + m];
        }
#pragma unroll
        for (int m = 0; m < 5; m++)
            dst[8192 + 24576 + (i * DD_ + dd) * 5 + m] = v[m];
    }
}

extern "C" void kernel_launch(void* const* d_in, const int* in_sizes, int n_in,
                              void* d_out, int out_size, void* d_ws, size_t ws_size,
                              hipStream_t stream) {
    const float* h_in = (const float*)d_in[0];
    const float* tij = (const float*)d_in[1];
    const float* r1 = (const float*)d_in[2];
    const float* r2 = (const float*)d_in[3];
    const float* x1 = (const float*)d_in[4];
    const float* x2 = (const float*)d_in[5];
    const float* ghi = (const float*)d_in[6];
    const float* ghj = (const float*)d_in[7];
    const float* Wq = (const float*)d_in[8];
    const float* Wk = (const float*)d_in[9];
    const float* Wv1 = (const float*)d_in[10];
    const float* bv1 = (const float*)d_in[11];
    const float* Wv2 = (const float*)d_in[12];
    const float* bv2 = (const float*)d_in[13];
    const float* Wp1 = (const float*)d_in[14];
    const float* bp1 = (const float*)d_in[15];
    const float* Wp2 = (const float*)d_in[16];
    const float* bp2 = (const float*)d_in[17];
    const float* Wev = (const float*)d_in[18];
    const float* Wc = (const float*)d_in[19];
    float* dst = (float*)d_out;

    float* w = (float*)d_ws;
    size_t off = 16;
    auto alloc = [&](size_t n) { float* p = w + off; off += n; return p; };
    float* q    = alloc(65536);
    float* k    = alloc(65536);
    float* a1   = alloc(131072);
    float* p1   = alloc(131072);
    float* VC   = alloc(327680);
    float* sn   = alloc(131072);
    float* rsd  = alloc(5120);
    float* M    = alloc(2621440);
    float* part = alloc(2621440);   // 4 x 655360 split-K partials
    float* pr   = alloc(PR_TOT);    // j-reduction partials

    k_front<<<dim3(128, 4), dim3(256), 0, stream>>>(h_in, ghi, ghj, Wq, Wk, Wv1, bv1, Wp1, bp1,
                                                    q, k, a1, p1);
    k_mlp2<<<dim3(80, KS2), dim3(256), 0, stream>>>(a1, p1, Wv2, Wp2, part);
    k_densim<<<dim3(128, 3), dim3(640), 0, stream>>>(tij, Wev, q, k, rsd, sn);
    k_postM<<<dim3(128, 5), dim3(256), 0, stream>>>(part, bv2, bp2, Wc, Wev, VC, M);
    k_outred<<<dim3(32, 5, 2), dim3(256), 0, stream>>>(M, VC, sn, rsd, tij, r1, r2, x1, x2, pr);
    k_red2<<<dim3(128), dim3(320), 0, stream>>>(pr, h_in, dst);
}

// Round 10
// 209.670 us; speedup vs baseline: 1.1501x; 1.1501x over previous
//
#include <hip/hip_runtime.h>
#include <hip/hip_bf16.h>

typedef __hip_bfloat16 bf16;
typedef __attribute__((ext_vector_type(8))) short short8;
typedef __attribute__((ext_vector_type(4))) float f32x4;

#define NN 128
#define DD_ 64
#define HH_ 8
#define DH_ 64
#define DI_ 512
#define SS_ 5
#define MLPD 1024
#define SDI 2560

// pr: 17 planes of 32jc*128i*64dd floats
#define PRPL 262144

__device__ __forceinline__ float wave_sum64(float v) {
#pragma unroll
    for (int off = 32; off > 0; off >>= 1) v += __shfl_xor(v, off, 64);
    return v;
}

__device__ __forceinline__ unsigned short f2bf_u(float f) {
    unsigned u = __float_as_uint(f);
    u += 0x7FFF + ((u >> 16) & 1);
    return (unsigned short)(u >> 16);
}
__device__ __forceinline__ float bfu2f(unsigned short s) {
    return __uint_as_float(((unsigned)s) << 16);
}
__device__ __forceinline__ unsigned pk2(unsigned short a, unsigned short b) {
    return (unsigned)a | ((unsigned)b << 16);
}

// K1: fused LN + q/k + mlp1, column-chunked. grid(128 i, 4 ch), block(256).
__global__ __launch_bounds__(256) void k_front(
    const float* __restrict__ h, const float* __restrict__ ghi, const float* __restrict__ ghj,
    const float* __restrict__ Wq, const float* __restrict__ Wk,
    const float* __restrict__ Wv1, const float* __restrict__ bv1,
    const float* __restrict__ Wp1, const float* __restrict__ bp1,
    float* __restrict__ q, float* __restrict__ k,
    float* __restrict__ a1, float* __restrict__ p1) {
    int i = blockIdx.x, ch = blockIdx.y, t = threadIdx.x;
    int d = t & 63;
    __shared__ float hib[DD_], hjb[DD_];
    float x = h[i * DD_ + d];
    float s = wave_sum64(x);
    float s2 = wave_sum64(x * x);
    float m = s * (1.0f / DD_);
    float v = s2 * (1.0f / DD_) - m * m;
    float r = rsqrtf(v + 1e-5f);
    float xc = (x - m) * r;
    if (t < 64) { hib[d] = xc * ghi[d]; hjb[d] = xc * ghj[d]; }
    __syncthreads();
    {
        int c = ch * 128 + (t & 127);
        const float* W = (t < 128) ? Wq : Wk;
        const float* hb = (t < 128) ? hib : hjb;
        float a = 0.f;
#pragma unroll 8
        for (int dd = 0; dd < DD_; dd++) a += hb[dd] * W[dd * DI_ + c];
        float* dstqk = (t < 128) ? q : k;
        dstqk[i * DI_ + c] = a;
    }
    {
        int c = ch * 256 + t;
        float av = 0.f, ap = 0.f;
#pragma unroll 4
        for (int dd = 0; dd < DD_; dd++) {
            float hv = hjb[dd];
            av += hv * Wv1[dd * MLPD + c];
            ap += hv * Wp1[dd * MLPD + c];
        }
        float xv = av + bv1[c], xp = ap + bp1[c];
        a1[i * MLPD + c] = xv / (1.0f + expf(-xv));
        p1[i * MLPD + c] = xp / (1.0f + expf(-xp));
    }
}

// K4: split-K MFMA GEMM (hi/lo bf16 compensation): part[ks][j][cc].
// grid(80 ct, 4 ks), block(256).
#define KS2 4
__global__ __launch_bounds__(256) void k_mlp2(const float* __restrict__ a1,
                                              const float* __restrict__ p1,
                                              const float* __restrict__ Wv2,
                                              const float* __restrict__ Wp2,
                                              float* __restrict__ part) {
    int ct = blockIdx.x, ks = blockIdx.y, t = threadIdx.x;
    int c0 = ct * 64;
    bool isp = c0 >= 2560;
    int c0l = c0 - (isp ? 2560 : 0);
    const float* __restrict__ src = isp ? p1 : a1;
    const float* __restrict__ W = isp ? Wp2 : Wv2;
    int kbase = ks * 256;
    __shared__ unsigned short Ahi[128][40], Alo[128][40];
    __shared__ unsigned short Bhi[64][40], Blo[64][40];
    int lane = t & 63, wv = t >> 6;
    int l15 = lane & 15, quad = lane >> 4;
    f32x4 acc[2][4];
#pragma unroll
    for (int mt = 0; mt < 2; mt++)
#pragma unroll
        for (int nt = 0; nt < 4; nt++) acc[mt][nt] = (f32x4){0.f, 0.f, 0.f, 0.f};
    int aj = t >> 1, ak = (t & 1) * 16;
    int bc = t & 63, bk = (t >> 6) * 8;
    for (int kc = 0; kc < 8; kc++) {
        int k0 = kbase + kc * 32;
        __syncthreads();
        {
            unsigned short h16[16], l16[16];
            const float* ap = &src[(size_t)aj * MLPD + k0 + ak];
#pragma unroll
            for (int e = 0; e < 16; e += 4) {
                float4 v = *(const float4*)(ap + e);
                float vv[4] = {v.x, v.y, v.z, v.w};
#pragma unroll
                for (int z = 0; z < 4; z++) {
                    unsigned short hb = f2bf_u(vv[z]);
                    h16[e + z] = hb;
                    l16[e + z] = f2bf_u(vv[z] - bfu2f(hb));
                }
            }
            *(uint4*)&Ahi[aj][ak] = make_uint4(pk2(h16[0], h16[1]), pk2(h16[2], h16[3]),
                                               pk2(h16[4], h16[5]), pk2(h16[6], h16[7]));
            *(uint4*)&Ahi[aj][ak + 8] = make_uint4(pk2(h16[8], h16[9]), pk2(h16[10], h16[11]),
                                                   pk2(h16[12], h16[13]), pk2(h16[14], h16[15]));
            *(uint4*)&Alo[aj][ak] = make_uint4(pk2(l16[0], l16[1]), pk2(l16[2], l16[3]),
                                               pk2(l16[4], l16[5]), pk2(l16[6], l16[7]));
            *(uint4*)&Alo[aj][ak + 8] = make_uint4(pk2(l16[8], l16[9]), pk2(l16[10], l16[11]),
                                                   pk2(l16[12], l16[13]), pk2(l16[14], l16[15]));
        }
        {
            unsigned short h8[8], l8[8];
#pragma unroll
            for (int e = 0; e < 8; e++) {
                float v = W[(size_t)(k0 + bk + e) * SDI + c0l + bc];
                unsigned short hb = f2bf_u(v);
                h8[e] = hb;
                l8[e] = f2bf_u(v - bfu2f(hb));
            }
            *(uint4*)&Bhi[bc][bk] = make_uint4(pk2(h8[0], h8[1]), pk2(h8[2], h8[3]),
                                               pk2(h8[4], h8[5]), pk2(h8[6], h8[7]));
            *(uint4*)&Blo[bc][bk] = make_uint4(pk2(l8[0], l8[1]), pk2(l8[2], l8[3]),
                                               pk2(l8[4], l8[5]), pk2(l8[6], l8[7]));
        }
        __syncthreads();
        int ko = quad * 8;
        short8 a_h0 = *(const short8*)&Ahi[(wv * 2 + 0) * 16 + l15][ko];
        short8 a_l0 = *(const short8*)&Alo[(wv * 2 + 0) * 16 + l15][ko];
        short8 a_h1 = *(const short8*)&Ahi[(wv * 2 + 1) * 16 + l15][ko];
        short8 a_l1 = *(const short8*)&Alo[(wv * 2 + 1) * 16 + l15][ko];
#pragma unroll
        for (int nt = 0; nt < 4; nt++) {
            short8 b_h = *(const short8*)&Bhi[nt * 16 + l15][ko];
            short8 b_l = *(const short8*)&Blo[nt * 16 + l15][ko];
            acc[0][nt] = __builtin_amdgcn_mfma_f32_16x16x32_bf16(a_h0, b_h, acc[0][nt], 0, 0, 0);
            acc[0][nt] = __builtin_amdgcn_mfma_f32_16x16x32_bf16(a_h0, b_l, acc[0][nt], 0, 0, 0);
            acc[0][nt] = __builtin_amdgcn_mfma_f32_16x16x32_bf16(a_l0, b_h, acc[0][nt], 0, 0, 0);
            acc[1][nt] = __builtin_amdgcn_mfma_f32_16x16x32_bf16(a_h1, b_h, acc[1][nt], 0, 0, 0);
            acc[1][nt] = __builtin_amdgcn_mfma_f32_16x16x32_bf16(a_h1, b_l, acc[1][nt], 0, 0, 0);
            acc[1][nt] = __builtin_amdgcn_mfma_f32_16x16x32_bf16(a_l1, b_h, acc[1][nt], 0, 0, 0);
        }
    }
#pragma unroll
    for (int mt = 0; mt < 2; mt++)
#pragma unroll
        for (int nt = 0; nt < 4; nt++)
#pragma unroll
            for (int r = 0; r < 4; r++) {
                int j = (wv * 2 + mt) * 16 + quad * 4 + r;
                int cc = c0 + nt * 16 + l15;
                part[(size_t)ks * 655360 + (size_t)j * 5120 + cc] = acc[mt][nt][r];
            }
}

// K_postM: part-reduce -> vals (LDS) -> VC; part-reduce -> pav (LDS) -> M (MFMA).
// grid(128 j, 5 s), block(256).
__global__ __launch_bounds__(256) void k_postM(const float* __restrict__ part,
                                               const float* __restrict__ bv2,
                                               const float* __restrict__ bp2,
                                               const float* __restrict__ Wc,
                                               const float* __restrict__ Wev,
                                               float* __restrict__ VC,
                                               float* __restrict__ M) {
    int j = blockIdx.x, s = blockIdx.y, t = threadIdx.x;
    int lane = t & 63, w = t >> 6;
    __shared__ float vlds[DI_];
    __shared__ float P[DI_];
    __shared__ unsigned short Ahi[64][72], Alo[64][72];
    __shared__ unsigned short Bhi[64][72], Blo[64][72];
#pragma unroll
    for (int r = 0; r < 2; r++) {
        int o = t + r * 256;
        int ev = s * 512 + o;
        int ep = 2560 + s * 512 + o;
        float sv = 0.f, sp = 0.f;
#pragma unroll
        for (int p = 0; p < KS2; p++) {
            sv += part[(size_t)p * 655360 + (size_t)j * 5120 + ev];
            sp += part[(size_t)p * 655360 + (size_t)j * 5120 + ep];
        }
        vlds[o] = sv + bv2[ev];
        P[o] = sp + bp2[s * 512 + o];
    }
    __syncthreads();
#pragma unroll
    for (int r = 0; r < 2; r++) {
        int o = t + r * 256;
        int dd = o & 63;
        int hb = o - dd;
        float acc2 = 0.f;
#pragma unroll 8
        for (int d2 = 0; d2 < DH_; d2++) acc2 += vlds[hb + d2] * Wc[(size_t)(hb + d2) * DD_ + dd];
        VC[(size_t)(j * SS_ + s) * DI_ + o] = acc2;
    }
    f32x4 acc[4];
#pragma unroll
    for (int n = 0; n < 4; n++) acc[n] = (f32x4){0.f, 0.f, 0.f, 0.f};
    for (int u0 = 0; u0 < DI_; u0 += 64) {
        __syncthreads();
        {
            int c = t >> 2, ug = (t & 3) * 16;
            const float* wevp = &Wev[(size_t)c * SDI + s * DI_ + u0 + ug];
            unsigned short ah[16], al[16];
#pragma unroll
            for (int e = 0; e < 16; e += 4) {
                float4 wv2 = *(const float4*)(wevp + e);
                float4 pv = *(const float4*)&P[u0 + ug + e];
                float av[4] = {wv2.x * pv.x, wv2.y * pv.y, wv2.z * pv.z, wv2.w * pv.w};
#pragma unroll
                for (int z = 0; z < 4; z++) {
                    unsigned short hh2 = f2bf_u(av[z]);
                    ah[e + z] = hh2;
                    al[e + z] = f2bf_u(av[z] - bfu2f(hh2));
                }
            }
            *(uint4*)&Ahi[c][ug] = make_uint4(pk2(ah[0], ah[1]), pk2(ah[2], ah[3]),
                                              pk2(ah[4], ah[5]), pk2(ah[6], ah[7]));
            *(uint4*)&Ahi[c][ug + 8] = make_uint4(pk2(ah[8], ah[9]), pk2(ah[10], ah[11]),
                                                  pk2(ah[12], ah[13]), pk2(ah[14], ah[15]));
            *(uint4*)&Alo[c][ug] = make_uint4(pk2(al[0], al[1]), pk2(al[2], al[3]),
                                              pk2(al[4], al[5]), pk2(al[6], al[7]));
            *(uint4*)&Alo[c][ug + 8] = make_uint4(pk2(al[8], al[9]), pk2(al[10], al[11]),
                                                  pk2(al[12], al[13]), pk2(al[14], al[15]));
        }
        {
            int dd = t & 63, ub = (t >> 6) * 16;
            unsigned short bh[16], bl[16];
#pragma unroll
            for (int e = 0; e < 16; e++) {
                float v = Wc[(size_t)(u0 + ub + e) * DD_ + dd];
                unsigned short hh2 = f2bf_u(v);
                bh[e] = hh2;
                bl[e] = f2bf_u(v - bfu2f(hh2));
            }
            *(uint4*)&Bhi[dd][ub] = make_uint4(pk2(bh[0], bh[1]), pk2(bh[2], bh[3]),
                                               pk2(bh[4], bh[5]), pk2(bh[6], bh[7]));
            *(uint4*)&Bhi[dd][ub + 8] = make_uint4(pk2(bh[8], bh[9]), pk2(bh[10], bh[11]),
                                                   pk2(bh[12], bh[13]), pk2(bh[14], bh[15]));
            *(uint4*)&Blo[dd][ub] = make_uint4(pk2(bl[0], bl[1]), pk2(bl[2], bl[3]),
                                               pk2(bl[4], bl[5]), pk2(bl[6], bl[7]));
            *(uint4*)&Blo[dd][ub + 8] = make_uint4(pk2(bl[8], bl[9]), pk2(bl[10], bl[11]),
                                                   pk2(bl[12], bl[13]), pk2(bl[14], bl[15]));
        }
        __syncthreads();
#pragma unroll
        for (int kk = 0; kk < 2; kk++) {
            int ko = kk * 32 + (lane >> 4) * 8;
            short8 a_h = *(const short8*)&Ahi[w * 16 + (lane & 15)][ko];
            short8 a_l = *(const short8*)&Alo[w * 16 + (lane & 15)][ko];
#pragma unroll
            for (int n = 0; n < 4; n++) {
                short8 b_h = *(const short8*)&Bhi[n * 16 + (lane & 15)][ko];
                short8 b_l = *(const short8*)&Blo[n * 16 + (lane & 15)][ko];
                acc[n] = __builtin_amdgcn_mfma_f32_16x16x32_bf16(a_h, b_h, acc[n], 0, 0, 0);
                acc[n] = __builtin_amdgcn_mfma_f32_16x16x32_bf16(a_h, b_l, acc[n], 0, 0, 0);
                acc[n] = __builtin_amdgcn_mfma_f32_16x16x32_bf16(a_l, b_h, acc[n], 0, 0, 0);
            }
        }
    }
    float* Mp = &M[(size_t)(j * SS_ + s) * 4096];
#pragma unroll
    for (int n = 0; n < 4; n++)
#pragma unroll
        for (int r = 0; r < 4; r++) {
            int c = w * 16 + (lane >> 4) * 4 + r;
            int dd = n * 16 + (lane & 15);
            Mp[c * 64 + dd] = acc[n][r];
        }
}

// K_densim: y<2 -> den halves (T-sum + EV + rsd); y==2 -> simnum. grid(128 i, 3), block(640).
__global__ __launch_bounds__(640) void k_densim(const float* __restrict__ tij,
                                                const float* __restrict__ Wev,
                                                const float* __restrict__ q,
                                                const float* __restrict__ k,
                                                float* __restrict__ rsd,
                                                float* __restrict__ sn) {
    int i = blockIdx.x, y = blockIdx.y, t = threadIdx.x;
    __shared__ float red[10][64];
    __shared__ float Tl[64];
    __shared__ float ql[DI_];
    if (y < 2) {
        int half = y;
        int c = t & 63, jw = t >> 6;
        float s = 0.f;
        for (int j = jw; j < NN; j += 10) s += tij[(size_t)(i * NN + j) * DD_ + c];
        red[jw][c] = s;
        if (t < DI_) ql[t] = q[i * DI_ + t];
        __syncthreads();
        if (t < 64) {
            float a = 0.f;
#pragma unroll
            for (int r2 = 0; r2 < 10; r2++) a += red[r2][t];
            Tl[t] = a;
        }
        __syncthreads();
#pragma unroll
        for (int kx = 0; kx < 2; kx++) {
            int u = half * 1280 + kx * 640 + t;
            float ev = 0.f;
#pragma unroll 8
            for (int cc = 0; cc < DD_; cc++) ev += Tl[cc] * Wev[(size_t)cc * SDI + u];
            float den = wave_sum64(ev * ql[u & 511]);
            if ((t & 63) == 0) {
                int g = u >> 6;
                int ss = g >> 3, hh = g & 7;
                rsd[i * 40 + hh * SS_ + ss] = 1.0f / den;
            }
        }
    } else {
        if (t < DI_) ql[t] = q[i * DI_ + t];
        __syncthreads();
        for (int e = t; e < 1024; e += 640) {
            int hh = e >> 7, j = e & 127;
            float a = 0.f;
            const float* kr = &k[(size_t)j * DI_ + hh * DH_];
            const float* qr = &ql[hh * DH_];
#pragma unroll 8
            for (int d = 0; d < DH_; d++) a += qr[d] * kr[d];
            sn[i * 1024 + hh * NN + j] = a;
        }
    }
}

// K_outred: fused out (MFMA E-term + VALU A-term) + j-partial reduction.
// Templated on S -> Lm constexpr -> accW in VGPRs. m-plane pr writes (coalesced).
// grid(32 jc, 5 s, 2 ic), block(256). 4 j x 64 i per block.
template <int S>
__device__ __forceinline__ void outred_body(
    const float* __restrict__ M, const float* __restrict__ VC,
    const float* __restrict__ sn, const float* __restrict__ rsd,
    const float* __restrict__ tij,
    const float* __restrict__ r1, const float* __restrict__ r2,
    const float* __restrict__ x1, const float* __restrict__ x2,
    float* __restrict__ pr) {
    constexpr int Lm = (S == 0) ? 1 : ((S == 1 || S == 3) ? 3 : 5);
    int jc = blockIdx.x, ic = blockIdx.z, t = threadIdx.x;
    int lane = t & 63, wv = t >> 6, l15 = lane & 15, quad = lane >> 4;
    __shared__ unsigned short Ahi[64][40], Alo[64][40];
    __shared__ unsigned short Bhi[64][40], Blo[64][40];
    __shared__ float VCl[DI_];
    __shared__ float snl[64][9];
    __shared__ float wl[320];
    float accW[Lm][4][4];
#pragma unroll
    for (int m = 0; m < Lm; m++)
#pragma unroll
        for (int nt = 0; nt < 4; nt++)
#pragma unroll
            for (int r = 0; r < 4; r++) accW[m][nt][r] = 0.f;
    int i0 = ic * 64;
    for (int jj = 0; jj < 4; jj++) {
        int j = jc * 4 + jj;
        __syncthreads();  // protect LDS from previous iteration's readers
        // stage per-j weights
        if (S == 1) {
            for (int e = t; e < 192; e += 256) wl[e] = r1[((i0 + e / 3) * NN + j) * 3 + e % 3];
        } else if (S == 2) {
            for (int e = t; e < 320; e += 256) wl[e] = r2[((i0 + e / 5) * NN + j) * 5 + e % 5];
        } else if (S == 3) {
            for (int e = t; e < 192; e += 256) wl[e] = x1[((size_t)j * DD_ + e / 3) * 3 + e % 3];
        } else if (S == 4) {
            for (int e = t; e < 320; e += 256) wl[e] = x2[((size_t)j * DD_ + e / 5) * 5 + e % 5];
        }
        // stage VC column and snr = sn*rsd
        VCl[t] = VC[(size_t)(j * SS_ + S) * DI_ + t];
        VCl[t + 256] = VC[(size_t)(j * SS_ + S) * DI_ + t + 256];
#pragma unroll
        for (int r = 0; r < 2; r++) {
            int e = t + r * 256;
            int il = e >> 3, hh = e & 7;
            snl[il][hh] = sn[(i0 + il) * 1024 + hh * NN + j] * rsd[(i0 + il) * 40 + hh * SS_ + S];
        }
        f32x4 acc_o[4];
#pragma unroll
        for (int nt = 0; nt < 4; nt++) acc_o[nt] = (f32x4){0.f, 0.f, 0.f, 0.f};
        // E-term: 2 K-chunks of 32 c
        for (int kc = 0; kc < 2; kc++) {
            if (kc) __syncthreads();
            {
                int il = t >> 2, cg = (t & 3) * 8;
                const float* tp = &tij[(size_t)((i0 + il) * NN + j) * DD_ + kc * 32 + cg];
                float4 va = *(const float4*)tp;
                float4 vb = *(const float4*)(tp + 4);
                float vv[8] = {va.x, va.y, va.z, va.w, vb.x, vb.y, vb.z, vb.w};
                unsigned short h8[8], l8[8];
#pragma unroll
                for (int z = 0; z < 8; z++) {
                    unsigned short hb = f2bf_u(vv[z]);
                    h8[z] = hb;
                    l8[z] = f2bf_u(vv[z] - bfu2f(hb));
                }
                *(uint4*)&Ahi[il][cg] = make_uint4(pk2(h8[0], h8[1]), pk2(h8[2], h8[3]),
                                                   pk2(h8[4], h8[5]), pk2(h8[6], h8[7]));
                *(uint4*)&Alo[il][cg] = make_uint4(pk2(l8[0], l8[1]), pk2(l8[2], l8[3]),
                                                   pk2(l8[4], l8[5]), pk2(l8[6], l8[7]));
            }
            {
                int dd = t & 63, cg = (t >> 6) * 8;
                unsigned short h8[8], l8[8];
#pragma unroll
                for (int e = 0; e < 8; e++) {
                    float v = M[(size_t)(j * SS_ + S) * 4096 + (size_t)(kc * 32 + cg + e) * 64 + dd];
                    unsigned short hb = f2bf_u(v);
                    h8[e] = hb;
                    l8[e] = f2bf_u(v - bfu2f(hb));
                }
                *(uint4*)&Bhi[dd][cg] = make_uint4(pk2(h8[0], h8[1]), pk2(h8[2], h8[3]),
                                                   pk2(h8[4], h8[5]), pk2(h8[6], h8[7]));
                *(uint4*)&Blo[dd][cg] = make_uint4(pk2(l8[0], l8[1]), pk2(l8[2], l8[3]),
                                                   pk2(l8[4], l8[5]), pk2(l8[6], l8[7]));
            }
            __syncthreads();
            int ko = quad * 8;
            short8 a_h = *(const short8*)&Ahi[wv * 16 + l15][ko];
            short8 a_l = *(const short8*)&Alo[wv * 16 + l15][ko];
#pragma unroll
            for (int nt = 0; nt < 4; nt++) {
                short8 b_h = *(const short8*)&Bhi[nt * 16 + l15][ko];
                short8 b_l = *(const short8*)&Blo[nt * 16 + l15][ko];
                acc_o[nt] = __builtin_amdgcn_mfma_f32_16x16x32_bf16(a_h, b_h, acc_o[nt], 0, 0, 0);
                acc_o[nt] = __builtin_amdgcn_mfma_f32_16x16x32_bf16(a_h, b_l, acc_o[nt], 0, 0, 0);
                acc_o[nt] = __builtin_amdgcn_mfma_f32_16x16x32_bf16(a_l, b_h, acc_o[nt], 0, 0, 0);
            }
        }
        // A-term in fp32 VALU: acc_o[nt][r] += sum_h snr[i][h]*VC[h*64+dd]
#pragma unroll
        for (int nt = 0; nt < 4; nt++)
#pragma unroll
            for (int r = 0; r < 4; r++) {
                int irow = wv * 16 + quad * 4 + r;
                float a = 0.f;
#pragma unroll
                for (int hh = 0; hh < 8; hh++)
                    a += snl[irow][hh] * VCl[hh * 64 + nt * 16 + l15];
                acc_o[nt][r] += a;
            }
        // weighted accumulation over j
        if (S == 0) {
#pragma unroll
            for (int nt = 0; nt < 4; nt++)
#pragma unroll
                for (int r = 0; r < 4; r++) accW[0][nt][r] += acc_o[nt][r];
        } else if (S <= 2) {
#pragma unroll
            for (int m = 0; m < Lm; m++)
#pragma unroll
                for (int r = 0; r < 4; r++) {
                    float wgt = wl[(wv * 16 + quad * 4 + r) * Lm + m];
#pragma unroll
                    for (int nt = 0; nt < 4; nt++) accW[m][nt][r] += wgt * acc_o[nt][r];
                }
        } else {
#pragma unroll
            for (int m = 0; m < Lm; m++)
#pragma unroll
                for (int nt = 0; nt < 4; nt++) {
                    float wgt = wl[(nt * 16 + l15) * Lm + m];
#pragma unroll
                    for (int r = 0; r < 4; r++) accW[m][nt][r] += wgt * acc_o[nt][r];
                }
        }
    }
    // coalesced m-plane writes
    constexpr size_t base = (S == 0) ? 0 : (S == 1) ? (size_t)PRPL
                          : (S == 2) ? 4 * (size_t)PRPL
                          : (S == 3) ? 9 * (size_t)PRPL : 12 * (size_t)PRPL;
#pragma unroll
    for (int m = 0; m < Lm; m++)
#pragma unroll
        for (int nt = 0; nt < 4; nt++)
#pragma unroll
            for (int r = 0; r < 4; r++) {
                int i = i0 + wv * 16 + quad * 4 + r;
                int dd = nt * 16 + l15;
                pr[base + (size_t)m * PRPL + ((size_t)(jc * 128 + i)) * 64 + dd] = accW[m][nt][r];
            }
}

__global__ __launch_bounds__(256) void k_outred(
    const float* __restrict__ M, const float* __restrict__ VC,
    const float* __restrict__ sn, const float* __restrict__ rsd,
    const float* __restrict__ tij,
    const float* __restrict__ r1, const float* __restrict__ r2,
    const float* __restrict__ x1, const float* __restrict__ x2,
    float* __restrict__ pr) {
    switch (blockIdx.y) {
        case 0: outred_body<0>(M, VC, sn, rsd, tij, r1, r2, x1, x2, pr); break;
        case 1: outred_body<1>(M, VC, sn, rsd, tij, r1, r2, x1, x2, pr); break;
        case 2: outred_body<2>(M, VC, sn, rsd, tij, r1, r2, x1, x2, pr); break;
        case 3: outred_body<3>(M, VC, sn, rsd, tij, r1, r2, x1, x2, pr); break;
        default: outred_body<4>(M, VC, sn, rsd, tij, r1, r2, x1, x2, pr); break;
    }
}

// K_red2: fold 32 jc-partials per plane + combine + store. grid(128), block(320).
__global__ void k_red2(const float* __restrict__ pr, const float* __restrict__ h,
                       float* __restrict__ dst) {
    int i = blockIdx.x, t = threadIdx.x;
    int s = t >> 6, dd = t & 63;
    if (s == 0) {
        float v = 0.f;
        for (int c = 0; c < 32; c++) v += pr[((size_t)(c * 128 + i)) * 64 + dd];
        dst[i * DD_ + dd] = h[i * DD_ + dd] + v;
    } else if (s == 3) {
        float v[3] = {0.f, 0.f, 0.f};
        for (int c = 0; c < 32; c++) {
            size_t ro = ((size_t)(c * 128 + i)) * 64 + dd;
#pragma unroll
            for (int m = 0; m < 3; m++)
                v[m] += pr[(1 + m) * (size_t)PRPL + ro] + pr[(9 + m) * (size_t)PRPL + ro];
        }
#pragma unroll
        for (int m = 0; m < 3; m++)
            dst[8192 + (i * DD_ + dd) * 3 + m] = v[m];
    } else if (s == 4) {
        float v[5] = {0.f, 0.f, 0.f, 0.f, 0.f};
        for (int c = 0; c < 32; c++) {
            size_t ro = ((size_t)(c * 128 + i)) * 64 + dd;
#pragma unroll
            for (int m = 0; m < 5; m++)
                v[m] += pr[(4 + m) * (size_t)PRPL + ro] + pr[(12 + m) * (size_t)PRPL + ro];
        }
#pragma unroll
        for (int m = 0; m < 5; m++)
            dst[8192 + 24576 + (i * DD_ + dd) * 5 + m] = v[m];
    }
}

extern "C" void kernel_launch(void* const* d_in, const int* in_sizes, int n_in,
                              void* d_out, int out_size, void* d_ws, size_t ws_size,
                              hipStream_t stream) {
    const float* h_in = (const float*)d_in[0];
    const float* tij = (const float*)d_in[1];
    const float* r1 = (const float*)d_in[2];
    const float* r2 = (const float*)d_in[3];
    const float* x1 = (const float*)d_in[4];
    const float* x2 = (const float*)d_in[5];
    const float* ghi = (const float*)d_in[6];
    const float* ghj = (const float*)d_in[7];
    const float* Wq = (const float*)d_in[8];
    const float* Wk = (const float*)d_in[9];
    const float* Wv1 = (const float*)d_in[10];
    const float* bv1 = (const float*)d_in[11];
    const float* Wv2 = (const float*)d_in[12];
    const float* bv2 = (const float*)d_in[13];
    const float* Wp1 = (const float*)d_in[14];
    const float* bp1 = (const float*)d_in[15];
    const float* Wp2 = (const float*)d_in[16];
    const float* bp2 = (const float*)d_in[17];
    const float* Wev = (const float*)d_in[18];
    const float* Wc = (const float*)d_in[19];
    float* dst = (float*)d_out;

    float* w = (float*)d_ws;
    size_t off = 16;
    auto alloc = [&](size_t n) { float* p = w + off; off += n; return p; };
    float* q    = alloc(65536);
    float* k    = alloc(65536);
    float* a1   = alloc(131072);
    float* p1   = alloc(131072);
    float* VC   = alloc(327680);
    float* sn   = alloc(131072);
    float* rsd  = alloc(5120);
    float* M    = alloc(2621440);
    float* part = alloc(2621440);         // 4 x 655360 split-K partials
    float* pr   = alloc(17 * (size_t)PRPL);  // 17 m-planes of j-reduction partials

    k_front<<<dim3(128, 4), dim3(256), 0, stream>>>(h_in, ghi, ghj, Wq, Wk, Wv1, bv1, Wp1, bp1,
                                                    q, k, a1, p1);
    k_mlp2<<<dim3(80, KS2), dim3(256), 0, stream>>>(a1, p1, Wv2, Wp2, part);
    k_densim<<<dim3(128, 3), dim3(640), 0, stream>>>(tij, Wev, q, k, rsd, sn);
    k_postM<<<dim3(128, 5), dim3(256), 0, stream>>>(part, bv2, bp2, Wc, Wev, VC, M);
    k_outred<<<dim3(32, 5, 2), dim3(256), 0, stream>>>(M, VC, sn, rsd, tij, r1, r2, x1, x2, pr);
    k_red2<<<dim3(128), dim3(320), 0, stream>>>(pr, h_in, dst);
}